// Round 16
// baseline (404.186 us; speedup 1.0000x reference)
//
#include <hip/hip_runtime.h>

#define BB 32
#define TT 243
#define JJ 17
#define CC 256
#define BJC (BB*JJ)          // 544
#define MM (BJC*TT)          // 132192 rows (compact: r = bj*TT + t)
#define FR (BJC*256)         // 139264 padded flat rows: flat = bj*256 + t
#define SIMP 244             // padded sim row stride
#define NEG_INF (-3.0e38f)
#define NSIMB (BJC*2)        // 1088 sim blocks
#define NUVB  (FR/128*2)     // 2176 uv blocks (128 rows x 256 cols each)

typedef __attribute__((ext_vector_type(8))) short bf16x8;
typedef __attribute__((ext_vector_type(4))) float f32x4;
typedef __attribute__((ext_vector_type(8))) _Float16 f16x8;
typedef __attribute__((ext_vector_type(4))) _Float16 f16x4;

__device__ __forceinline__ unsigned short f2bf(float f) {
  unsigned int u = __float_as_uint(f);
  u = (u + 0x7fffu + ((u >> 16) & 1u)) >> 16;   // RNE
  return (unsigned short)u;
}
__device__ __forceinline__ float bf2f(unsigned short s) {
  return __uint_as_float(((unsigned int)s) << 16);
}

// async global->LDS, 16B per lane: lds dest = uniform base + lane*16
__device__ __forceinline__ void gld16(const void* g, void* l) {
  __builtin_amdgcn_global_load_lds(
      (__attribute__((address_space(1))) void*)(g),
      (__attribute__((address_space(3))) void*)(l), 16, 0, 0);
}

// ---------- K0a: W_u,W_v f32 [C,C] -> wcp f16 [4 ksteps][512][64] (swizzled) ----------
__launch_bounds__(256)
__global__ void k_prep_w(const float* __restrict__ Wu, const float* __restrict__ Wv,
                         _Float16* __restrict__ wcp) {
  const int r = blockIdx.x * 4 + (threadIdx.x >> 6);   // 0..511
  const int l = threadIdx.x & 63;
  const float* src = ((r < CC) ? (Wu + (size_t)r * CC) : (Wv + (size_t)(r - CC) * CC)) + l * 4;
  float4 v = *reinterpret_cast<const float4*>(src);
  f16x4 hv = (f16x4){(_Float16)v.x, (_Float16)v.y, (_Float16)v.z, (_Float16)v.w};
  const int ks = l >> 4;                 // k-plane 0..3 (64 f16 each)
  const int u  = (l & 15) >> 1;          // 16B unit 0..7
  const int s  = u ^ (r & 7);            // bank swizzle slot
  *reinterpret_cast<f16x4*>(wcp + ((size_t)ks * 512 + r) * 64 + s * 8 + (l & 1) * 4) = hv;
}

// ---------- K0b: x -> xqh/xql (f16 hi + residual lo), panel-padded flat layout ----------
__launch_bounds__(256)
__global__ void k_prep_x(const float* __restrict__ x,
                         _Float16* __restrict__ xqh, _Float16* __restrict__ xql) {
  const int r = blockIdx.x * 4 + (threadIdx.x >> 6);   // compact row 0..MM-1
  const int l = threadIdx.x & 63;
  const int bj = r / TT, t = r - bj * TT;
  const int b = bj / JJ, j = bj - b * JJ;
  float4 v = *reinterpret_cast<const float4*>(
      x + ((size_t)(b * TT + t) * JJ + j) * CC + l * 4);
  _Float16 h0 = (_Float16)v.x, h1 = (_Float16)v.y, h2 = (_Float16)v.z, h3 = (_Float16)v.w;
  f16x4 hv = (f16x4){h0, h1, h2, h3};
  f16x4 lv = (f16x4){(_Float16)(v.x - (float)h0), (_Float16)(v.y - (float)h1),
                     (_Float16)(v.z - (float)h2), (_Float16)(v.w - (float)h3)};
  const int fr = bj * 256 + t;            // padded flat row
  const int ks = l >> 4;
  const int u  = (l & 15) >> 1;
  const int s  = u ^ (t & 7);             // == fr&7 since bj*256 % 8 == 0
  const size_t off = ((size_t)ks * FR + fr) * 64 + s * 8 + (l & 1) * 4;
  *reinterpret_cast<f16x4*>(xqh + off) = hv;
  *reinterpret_cast<f16x4*>(xql + off) = lv;
}

// ---------- K1+K2 FUSED: sim (bids < NSIMB) and u,v GEMM (bids >= NSIMB) ----------
// sim path: identical to r15 k_sim (XCD-paired row-halves, transposed C-write).
// uv path: 512-thr block = 128 rows x 256 cols (cu=0 -> u, cu=1 -> v); wave
// tile 32x128, bfv loaded 4 at a time to keep VGPR <= ~64 (+64 acc).
// Co-resident sim/uv blocks overlap MFMA-heavy and store/latency phases.
__launch_bounds__(512, 4)
__global__ void k_main(const _Float16* __restrict__ xqh, const _Float16* __restrict__ xql,
                       const _Float16* __restrict__ wcp,
                       const float* __restrict__ bu, const float* __restrict__ bv,
                       float* __restrict__ sim,
                       unsigned short* __restrict__ uo, unsigned short* __restrict__ vo) {
  __shared__ __align__(16) char LB[65536];
  const int tid = threadIdx.x, lane = tid & 63, wid = tid >> 6;
  const int l15 = lane & 15, lg = lane >> 4;
  const size_t lsrc = (size_t)(lane >> 3) * 64 + (lane & 7) * 8;

  if (blockIdx.x < NSIMB) {
    // ================= sim path =================
    _Float16* Sh = (_Float16*)LB;                 // 32 KB
    _Float16* Sl = (_Float16*)(LB + 32768);       // 32 KB
    const int bid = blockIdx.x;
    const int g = bid >> 4, s_ = bid & 15;
    const int bj = g * 8 + (s_ & 7);              // 544 = 68*8 -> bijective
    const int rh = s_ >> 3;
    const int wr = wid >> 2, wc = wid & 3;
    const int rowbase = rh * 128 + wr * 64;
    const size_t rb = (size_t)bj * 256;

    f32x4 acc[4][4];
    #pragma unroll
    for (int i = 0; i < 4; i++)
      #pragma unroll
      for (int j = 0; j < 4; j++) acc[i][j] = (f32x4){0.f, 0.f, 0.f, 0.f};

    for (int ks = 0; ks < 4; ++ks) {
      {
        const _Float16* ph = xqh + ((size_t)ks * FR + rb) * 64;
        const _Float16* pl = xql + ((size_t)ks * FR + rb) * 64;
        #pragma unroll
        for (int c = 0; c < 4; ++c) {
          const int row0 = (wid * 4 + c) * 8;
          gld16(ph + (size_t)row0 * 64 + lsrc, Sh + row0 * 64);
          gld16(pl + (size_t)row0 * 64 + lsrc, Sl + row0 * 64);
        }
      }
      __syncthreads();
      #pragma unroll
      for (int kh = 0; kh < 2; ++kh) {
        f16x8 bhv[4], blv[4];
        #pragma unroll
        for (int j = 0; j < 4; ++j) {
          int rc = wc * 64 + j * 16 + l15;
          int sl = ((kh * 4 + lg) ^ (rc & 7)) * 8;
          bhv[j] = *reinterpret_cast<const f16x8*>(&Sh[rc * 64 + sl]);
          blv[j] = *reinterpret_cast<const f16x8*>(&Sl[rc * 64 + sl]);
        }
        #pragma unroll
        for (int i = 0; i < 4; ++i) {
          int rl = rowbase + i * 16 + l15;
          int sl = ((kh * 4 + lg) ^ (rl & 7)) * 8;
          f16x8 ah = *reinterpret_cast<const f16x8*>(&Sh[rl * 64 + sl]);
          f16x8 al = *reinterpret_cast<const f16x8*>(&Sl[rl * 64 + sl]);
          #pragma unroll
          for (int j = 0; j < 4; ++j) {
            acc[i][j] = __builtin_amdgcn_mfma_f32_16x16x32_f16(ah, bhv[j], acc[i][j], 0, 0, 0);
            acc[i][j] = __builtin_amdgcn_mfma_f32_16x16x32_f16(ah, blv[j], acc[i][j], 0, 0, 0);
            acc[i][j] = __builtin_amdgcn_mfma_f32_16x16x32_f16(al, bhv[j], acc[i][j], 0, 0, 0);
          }
        }
      }
      if (ks < 3) __syncthreads();
    }

    const size_t sbase = (size_t)bj * TT * SIMP;
    #pragma unroll
    for (int j = 0; j < 4; ++j) {
      int c = wc * 64 + j * 16 + l15;              // transposed row (symmetry)
      if (c < TT) {
        #pragma unroll
        for (int i = 0; i < 4; ++i) {
          int n0 = rowbase + i * 16 + lg * 4;
          if (n0 + 3 < TT) {
            *reinterpret_cast<float4*>(sim + sbase + (size_t)c * SIMP + n0) =
              (float4){acc[i][j][0], acc[i][j][1], acc[i][j][2], acc[i][j][3]};
          } else {
            #pragma unroll
            for (int q = 0; q < 4; ++q)
              if (n0 + q < TT) sim[sbase + (size_t)c * SIMP + n0 + q] = acc[i][j][q];
          }
        }
      }
    }
  } else {
    // ================= uv path =================
    _Float16* As = (_Float16*)LB;                 // 16 KB: 128 rows x 64
    _Float16* Bs = (_Float16*)(LB + 16384);       // 32 KB: 256 w-rows x 64
    const int bid2 = blockIdx.x - NSIMB;
    const int cu = bid2 & 1;                      // 0 -> u, 1 -> v
    const int panel = bid2 >> 1;                  // 0..1087
    const int m0 = panel * 128;
    const int rm = (wid & 3) * 32;                // wave rows
    const int ch = wid >> 2;                      // wave col-half (0/1)

    const float* bsrc = cu ? bv : bu;
    unsigned short* osrc = cu ? vo : uo;

    f32x4 acc[2][8];
    #pragma unroll
    for (int i = 0; i < 2; i++)
      #pragma unroll
      for (int j = 0; j < 8; j++) acc[i][j] = (f32x4){0.f, 0.f, 0.f, 0.f};

    for (int ks = 0; ks < 4; ++ks) {
      #pragma unroll
      for (int c = 0; c < 6; ++c) {               // 48 chunks x 1KB, 6 per wave
        int chk = wid * 6 + c;
        if (chk < 16) {
          int row0 = chk * 8;
          gld16(xqh + ((size_t)ks * FR + m0 + row0) * 64 + lsrc, As + row0 * 64);
        } else {
          int row0 = (chk - 16) * 8;
          gld16(wcp + ((size_t)ks * 512 + cu * 256 + row0) * 64 + lsrc, Bs + row0 * 64);
        }
      }
      __syncthreads();
      #pragma unroll
      for (int kh = 0; kh < 2; ++kh) {
        f16x8 af[2];
        #pragma unroll
        for (int i = 0; i < 2; ++i) {
          int rl = rm + i * 16 + l15;
          af[i] = *reinterpret_cast<const f16x8*>(&As[rl * 64 + ((kh * 4 + lg) ^ (rl & 7)) * 8]);
        }
        #pragma unroll
        for (int jh = 0; jh < 2; ++jh) {
          f16x8 bfv[4];
          #pragma unroll
          for (int j = 0; j < 4; ++j) {
            int rb2 = ch * 128 + jh * 64 + j * 16 + l15;
            bfv[j] = *reinterpret_cast<const f16x8*>(&Bs[rb2 * 64 + ((kh * 4 + lg) ^ (rb2 & 7)) * 8]);
          }
          #pragma unroll
          for (int i = 0; i < 2; ++i)
            #pragma unroll
            for (int j = 0; j < 4; ++j)
              acc[i][jh * 4 + j] =
                __builtin_amdgcn_mfma_f32_16x16x32_f16(af[i], bfv[j], acc[i][jh * 4 + j], 0, 0, 0);
        }
      }
      if (ks < 3) __syncthreads();
    }

    #pragma unroll
    for (int i = 0; i < 2; ++i) {
      #pragma unroll
      for (int q = 0; q < 4; ++q) {
        int gf = m0 + rm + i * 16 + lg * 4 + q;    // padded flat row
        int t = gf & 255, bj = gf >> 8;
        if (t < TT) {
          size_t gm = (size_t)bj * TT + t;
          #pragma unroll
          for (int j = 0; j < 8; ++j) {
            int col = ch * 128 + j * 16 + l15;
            osrc[gm * CC + col] = f2bf(acc[i][j][q] + bsrc[col]);
          }
        }
      }
    }
  }
}

// ---------- K3a: thr via bitonic top-4 butterfly; dis, deg, nbr list, masks ----------
__launch_bounds__(256)
__global__ void k_topk(const float* __restrict__ sim,
                       float* __restrict__ dis_o,
                       unsigned long long* __restrict__ mask_o,
                       unsigned char* __restrict__ nbr_o,
                       unsigned char* __restrict__ deg_o) {
  const int l = threadIdx.x & 63, wv = threadIdx.x >> 6;
  const int r = blockIdx.x * 4 + wv;               // MM % 4 == 0
  const float* row = sim + (size_t)r * SIMP;
  float o0 = row[l];
  float o1 = row[l + 64];
  float o2 = row[l + 128];
  float o3 = (l + 192 < TT) ? row[l + 192] : NEG_INF;
  float v0 = o0, v1 = o1, v2 = o2, v3 = o3;
  { float mx, mn;
    mx=fmaxf(v0,v1); mn=fminf(v0,v1); v0=mx; v1=mn;
    mx=fmaxf(v2,v3); mn=fminf(v2,v3); v2=mx; v3=mn;
    mx=fmaxf(v0,v2); mn=fminf(v0,v2); v0=mx; v2=mn;
    mx=fmaxf(v1,v3); mn=fminf(v1,v3); v1=mx; v3=mn;
    mx=fmaxf(v1,v2); mn=fminf(v1,v2); v1=mx; v2=mn; }
  #pragma unroll
  for (int off = 1; off < 64; off <<= 1) {
    float b0 = __shfl_xor(v0, off), b1 = __shfl_xor(v1, off),
          b2 = __shfl_xor(v2, off), b3 = __shfl_xor(v3, off);
    float t0 = fmaxf(v0, b3), t1 = fmaxf(v1, b2),
          t2 = fmaxf(v2, b1), t3 = fmaxf(v3, b0);
    float mx, mn;
    mx=fmaxf(t0,t2); mn=fminf(t0,t2); t0=mx; t2=mn;
    mx=fmaxf(t1,t3); mn=fminf(t1,t3); t1=mx; t3=mn;
    mx=fmaxf(t0,t1); mn=fminf(t0,t1); t0=mx; t1=mn;
    mx=fmaxf(t2,t3); mn=fminf(t2,t3); t2=mx; t3=mn;
    v0=t0; v1=t1; v2=t2; v3=t3;
  }
  const float thr = v3;                            // 4th largest (w/ duplicates)

  unsigned long long m0 = __ballot(o0 >= thr);
  unsigned long long m1 = __ballot(o1 >= thr);
  unsigned long long m2 = __ballot(o2 >= thr);
  unsigned long long m3 = __ballot(o3 >= thr);
  const unsigned long long below = (1ull << l) - 1ull;
  const int b0 = __popcll(m0);
  const int b1 = b0 + __popcll(m1);
  const int b2 = b1 + __popcll(m2);
  const size_t r8 = (size_t)r * 8;
  if (o0 >= thr) { int q = __popcll(m0 & below);      if (q < 8) nbr_o[r8 + q] = (unsigned char)l; }
  if (o1 >= thr) { int q = b0 + __popcll(m1 & below); if (q < 8) nbr_o[r8 + q] = (unsigned char)(64 + l); }
  if (o2 >= thr) { int q = b1 + __popcll(m2 & below); if (q < 8) nbr_o[r8 + q] = (unsigned char)(128 + l); }
  if (o3 >= thr) { int q = b2 + __popcll(m3 & below); if (q < 8) nbr_o[r8 + q] = (unsigned char)(192 + l); }
  if (l == 0) {
    int deg = b2 + __popcll(m3);
    dis_o[r] = rsqrtf((float)deg);
    deg_o[r] = (unsigned char)((deg > 255) ? 255 : deg);
    mask_o[(size_t)r * 4 + 0] = m0;
    mask_o[(size_t)r * 4 + 1] = m1;
    mask_o[(size_t)r * 4 + 2] = m2;
    mask_o[(size_t)r * 4 + 3] = m3;
  }
}

// ---------- K3b: h = norm_adj @ v + u  (list gather: independent loads) ----------
__launch_bounds__(512)
__global__ void k_agg(const unsigned char* __restrict__ nbr,
                      const unsigned char* __restrict__ degv,
                      const unsigned long long* __restrict__ mask,
                      const float* __restrict__ dis,
                      const unsigned short* __restrict__ u,
                      const unsigned short* __restrict__ v,
                      unsigned short* __restrict__ h,
                      float* __restrict__ p1, float* __restrict__ p2) {
  __shared__ float dis_l[256];
  const int bj = blockIdx.x;
  const int tid = threadIdx.x, lane = tid & 63, wid = tid >> 6;
  if (tid < TT) dis_l[tid] = dis[(size_t)bj * TT + tid];
  __syncthreads();
  const int start = blockIdx.y * 122;
  const int cnt = blockIdx.y ? (TT - 122) : 122;
  const size_t pbase = (size_t)bj * TT;
  const int co = lane * 4;
  for (int rl = wid; rl < cnt; rl += 8) {
    const int t = start + rl;
    const size_t r = pbase + t;
    const float dr = dis_l[t];
    const int dg = degv[r];
    const unsigned long long nb = *reinterpret_cast<const unsigned long long*>(nbr + r * 8);
    ushort4 uu = *reinterpret_cast<const ushort4*>(u + r * CC + co);
    float a0 = bf2f(uu.x), a1 = bf2f(uu.y), a2 = bf2f(uu.z), a3 = bf2f(uu.w);
    if (dg <= 8) {
      const int i0 = (int)(nb & 255), i1 = (int)((nb >> 8) & 255),
                i2 = (int)((nb >> 16) & 255), i3 = (int)((nb >> 24) & 255);
      ushort4 w0v = *reinterpret_cast<const ushort4*>(v + (pbase + i0) * CC + co);
      ushort4 w1v = *reinterpret_cast<const ushort4*>(v + (pbase + i1) * CC + co);
      ushort4 w2v = *reinterpret_cast<const ushort4*>(v + (pbase + i2) * CC + co);
      ushort4 w3v = *reinterpret_cast<const ushort4*>(v + (pbase + i3) * CC + co);
      const float w0 = dr * dis_l[i0], w1 = dr * dis_l[i1],
                  w2 = dr * dis_l[i2], w3 = dr * dis_l[i3];
      a0 = __builtin_fmaf(w0, bf2f(w0v.x), a0); a1 = __builtin_fmaf(w0, bf2f(w0v.y), a1);
      a2 = __builtin_fmaf(w0, bf2f(w0v.z), a2); a3 = __builtin_fmaf(w0, bf2f(w0v.w), a3);
      a0 = __builtin_fmaf(w1, bf2f(w1v.x), a0); a1 = __builtin_fmaf(w1, bf2f(w1v.y), a1);
      a2 = __builtin_fmaf(w1, bf2f(w1v.z), a2); a3 = __builtin_fmaf(w1, bf2f(w1v.w), a3);
      a0 = __builtin_fmaf(w2, bf2f(w2v.x), a0); a1 = __builtin_fmaf(w2, bf2f(w2v.y), a1);
      a2 = __builtin_fmaf(w2, bf2f(w2v.z), a2); a3 = __builtin_fmaf(w2, bf2f(w2v.w), a3);
      a0 = __builtin_fmaf(w3, bf2f(w3v.x), a0); a1 = __builtin_fmaf(w3, bf2f(w3v.y), a1);
      a2 = __builtin_fmaf(w3, bf2f(w3v.z), a2); a3 = __builtin_fmaf(w3, bf2f(w3v.w), a3);
      #pragma unroll
      for (int e = 4; e < 8; ++e) {
        if (e < dg) {
          const int ix = (int)((nb >> (8 * e)) & 255);
          const float we = dr * dis_l[ix];
          ushort4 vv = *reinterpret_cast<const ushort4*>(v + (pbase + ix) * CC + co);
          a0 = __builtin_fmaf(we, bf2f(vv.x), a0); a1 = __builtin_fmaf(we, bf2f(vv.y), a1);
          a2 = __builtin_fmaf(we, bf2f(vv.z), a2); a3 = __builtin_fmaf(we, bf2f(vv.w), a3);
        }
      }
    } else {                                     // rare tie overflow: mask decode
      #pragma unroll
      for (int w4 = 0; w4 < 4; ++w4) {
        unsigned long long m = mask[r * 4 + w4];
        while (m) {
          int i = __ffsll(m) - 1;
          m &= m - 1;
          int idx = w4 * 64 + i;
          float w = dr * dis_l[idx];
          ushort4 vv = *reinterpret_cast<const ushort4*>(v + (pbase + idx) * CC + co);
          a0 = __builtin_fmaf(w, bf2f(vv.x), a0);
          a1 = __builtin_fmaf(w, bf2f(vv.y), a1);
          a2 = __builtin_fmaf(w, bf2f(vv.z), a2);
          a3 = __builtin_fmaf(w, bf2f(vv.w), a3);
        }
      }
    }
    ushort4 hh;
    hh.x = f2bf(a0); hh.y = f2bf(a1); hh.z = f2bf(a2); hh.w = f2bf(a3);
    *reinterpret_cast<ushort4*>(h + r * CC + co) = hh;
    float s1 = a0 + a1 + a2 + a3;
    float s2 = a0*a0 + a1*a1 + a2*a2 + a3*a3;
    #pragma unroll
    for (int off = 1; off < 64; off <<= 1) { s1 += __shfl_xor(s1, off); s2 += __shfl_xor(s2, off); }
    if (lane == 0) { p1[r] = s1; p2[r] = s2; }
  }
}

// ---------- K4: BN stats per t -> scale/shift ----------
__global__ void k_bnstat(const float* __restrict__ p1, const float* __restrict__ p2,
                         const float* __restrict__ gamma, const float* __restrict__ beta,
                         float* __restrict__ scale, float* __restrict__ shift) {
  __shared__ float sA[256], sB[256];
  const int t = blockIdx.x;
  const int tid = threadIdx.x;
  float a = 0.f, b2 = 0.f;
  for (int bj = tid; bj < BJC; bj += 256) {
    a  += p1[bj * TT + t];
    b2 += p2[bj * TT + t];
  }
  sA[tid] = a; sB[tid] = b2;
  __syncthreads();
  for (int s = 128; s > 0; s >>= 1) {
    if (tid < s) { sA[tid] += sA[tid + s]; sB[tid] += sB[tid + s]; }
    __syncthreads();
  }
  if (tid == 0) {
    const float invN = 1.0f / (float)(BJC * CC);
    float mean = sA[0] * invN;
    float var  = sB[0] * invN - mean * mean;
    float sc   = rsqrtf(var + 1e-5f) * gamma[t];
    scale[t] = sc;
    shift[t] = beta[t] - mean * sc;
  }
}

// ---------- K5: out = relu(x + h*scale + shift), back to [B,T,J,C] ----------
__global__ void k_out(const float* __restrict__ x, const unsigned short* __restrict__ h,
                      const float* __restrict__ scale, const float* __restrict__ shift,
                      float* __restrict__ out) {
  int g = blockIdx.x * 256 + threadIdx.x;
  if (g >= MM * (CC/4)) return;
  int c4  = g & 63;
  int rowx = g >> 6;
  int b   = rowx / (TT*JJ);
  int rem = rowx - b*(TT*JJ);
  int t   = rem / JJ;
  int j   = rem - t*JJ;
  size_t hoff = ((size_t)(b*JJ + j) * TT + t) * CC + c4*4;
  float4 xv = *reinterpret_cast<const float4*>(x + (size_t)rowx*CC + c4*4);
  ushort4 hv = *reinterpret_cast<const ushort4*>(h + hoff);
  float sc = scale[t], sh = shift[t];
  float4 o;
  o.x = fmaxf(xv.x + bf2f(hv.x)*sc + sh, 0.f);
  o.y = fmaxf(xv.y + bf2f(hv.y)*sc + sh, 0.f);
  o.z = fmaxf(xv.z + bf2f(hv.z)*sc + sh, 0.f);
  o.w = fmaxf(xv.w + bf2f(hv.w)*sc + sh, 0.f);
  *reinterpret_cast<float4*>(out + (size_t)rowx*CC + c4*4) = o;
}

extern "C" void kernel_launch(void* const* d_in, const int* in_sizes, int n_in,
                              void* d_out, int out_size, void* d_ws, size_t ws_size,
                              hipStream_t stream) {
  const float* x     = (const float*)d_in[0];
  const float* Wu    = (const float*)d_in[1];
  const float* bu    = (const float*)d_in[2];
  const float* Wv    = (const float*)d_in[3];
  const float* bv    = (const float*)d_in[4];
  const float* gamma = (const float*)d_in[5];
  const float* beta  = (const float*)d_in[6];
  float* out = (float*)d_out;

  char* ws = (char*)d_ws;
  size_t off = 0;
  auto alloc = [&](size_t bytes) -> void* {
    void* p = ws + off;
    off = (off + bytes + 255) & ~(size_t)255;
    return p;
  };
  _Float16* xqh = (_Float16*)alloc((size_t)4 * FR * 64 * 2);      // 71.3MB
  _Float16* xql = (_Float16*)alloc((size_t)4 * FR * 64 * 2);      // 71.3MB
  _Float16* wcp = (_Float16*)alloc((size_t)4 * 512 * 64 * 2);
  float* sim = (float*)alloc((size_t)BJC * TT * SIMP * 4);        // 129MB
  float* dis = (float*)alloc((size_t)MM * 4);
  unsigned long long* msk = (unsigned long long*)alloc((size_t)MM * 4 * 8);
  unsigned char* nbr = (unsigned char*)alloc((size_t)MM * 8);
  unsigned char* deg = (unsigned char*)alloc((size_t)MM);
  float* p1    = (float*)alloc((size_t)MM * 4);
  float* p2    = (float*)alloc((size_t)MM * 4);
  float* scale = (float*)alloc(1024);
  float* shift = (float*)alloc(1024);
  unsigned short* u = (unsigned short*)alloc((size_t)MM * CC * 2); // 67.7MB
  unsigned short* v = (unsigned short*)alloc((size_t)MM * CC * 2); // 67.7MB
  // h aliases xql (dead after k_main's sim reads; k_agg runs later)
  unsigned short* h = (unsigned short*)xql;

  if (ws_size < off) {
    hipMemsetAsync(d_out, 0, (size_t)out_size * 4, stream);
    return;
  }

  k_prep_w<<<dim3(512/4), dim3(256), 0, stream>>>(Wu, Wv, wcp);
  k_prep_x<<<dim3(MM/4), dim3(256), 0, stream>>>(x, xqh, xql);
  k_main <<<dim3(NSIMB + NUVB), dim3(512), 0, stream>>>(xqh, xql, wcp, bu, bv, sim, u, v);
  k_topk <<<dim3(MM/4), dim3(256), 0, stream>>>(sim, dis, msk, nbr, deg);
  k_agg  <<<dim3(BJC, 2), dim3(512), 0, stream>>>(nbr, deg, msk, dis, u, v, h, p1, p2);
  k_bnstat<<<dim3(TT), dim3(256), 0, stream>>>(p1, p2, gamma, beta, scale, shift);
  k_out  <<<dim3((MM*(CC/4) + 255)/256), dim3(256), 0, stream>>>(x, h, scale, shift, out);
}

// Round 17
// 338.210 us; speedup vs baseline: 1.1951x; 1.1951x over previous
//
#include <hip/hip_runtime.h>

#define BB 32
#define TT 243
#define JJ 17
#define CC 256
#define BJC (BB*JJ)          // 544
#define MM (BJC*TT)          // 132192 rows (compact: r = bj*TT + t)
#define FR (BJC*256)         // 139264 padded flat rows: flat = bj*256 + t
#define NEG_INF (-3.0e38f)

typedef __attribute__((ext_vector_type(8))) short bf16x8;
typedef __attribute__((ext_vector_type(4))) float f32x4;
typedef __attribute__((ext_vector_type(8))) _Float16 f16x8;
typedef __attribute__((ext_vector_type(4))) _Float16 f16x4;

__device__ __forceinline__ unsigned short f2bf(float f) {
  unsigned int u = __float_as_uint(f);
  u = (u + 0x7fffu + ((u >> 16) & 1u)) >> 16;   // RNE
  return (unsigned short)u;
}
__device__ __forceinline__ float bf2f(unsigned short s) {
  return __uint_as_float(((unsigned int)s) << 16);
}

// async global->LDS, 16B per lane: lds dest = uniform base + lane*16
__device__ __forceinline__ void gld16(const void* g, void* l) {
  __builtin_amdgcn_global_load_lds(
      (__attribute__((address_space(1))) void*)(g),
      (__attribute__((address_space(3))) void*)(l), 16, 0, 0);
}

// ---------- K0a: W_u,W_v f32 [C,C] -> wcp f16 [4 ksteps][512][64] (swizzled) ----------
__launch_bounds__(256)
__global__ void k_prep_w(const float* __restrict__ Wu, const float* __restrict__ Wv,
                         _Float16* __restrict__ wcp) {
  const int r = blockIdx.x * 4 + (threadIdx.x >> 6);   // 0..511
  const int l = threadIdx.x & 63;
  const float* src = ((r < CC) ? (Wu + (size_t)r * CC) : (Wv + (size_t)(r - CC) * CC)) + l * 4;
  float4 v = *reinterpret_cast<const float4*>(src);
  f16x4 hv = (f16x4){(_Float16)v.x, (_Float16)v.y, (_Float16)v.z, (_Float16)v.w};
  const int ks = l >> 4;                 // k-plane 0..3 (64 f16 each)
  const int u  = (l & 15) >> 1;          // 16B unit 0..7
  const int s  = u ^ (r & 7);            // bank swizzle slot
  *reinterpret_cast<f16x4*>(wcp + ((size_t)ks * 512 + r) * 64 + s * 8 + (l & 1) * 4) = hv;
}

// ---------- K0b: x -> xqh/xql (f16 hi + residual lo), panel-padded flat layout ----------
__launch_bounds__(256)
__global__ void k_prep_x(const float* __restrict__ x,
                         _Float16* __restrict__ xqh, _Float16* __restrict__ xql) {
  const int r = blockIdx.x * 4 + (threadIdx.x >> 6);   // compact row 0..MM-1
  const int l = threadIdx.x & 63;
  const int bj = r / TT, t = r - bj * TT;
  const int b = bj / JJ, j = bj - b * JJ;
  float4 v = *reinterpret_cast<const float4*>(
      x + ((size_t)(b * TT + t) * JJ + j) * CC + l * 4);
  _Float16 h0 = (_Float16)v.x, h1 = (_Float16)v.y, h2 = (_Float16)v.z, h3 = (_Float16)v.w;
  f16x4 hv = (f16x4){h0, h1, h2, h3};
  f16x4 lv = (f16x4){(_Float16)(v.x - (float)h0), (_Float16)(v.y - (float)h1),
                     (_Float16)(v.z - (float)h2), (_Float16)(v.w - (float)h3)};
  const int fr = bj * 256 + t;            // padded flat row
  const int ks = l >> 4;
  const int u  = (l & 15) >> 1;
  const int s  = u ^ (t & 7);             // == fr&7 since bj*256 % 8 == 0
  const size_t off = ((size_t)ks * FR + fr) * 64 + s * 8 + (l & 1) * 4;
  *reinterpret_cast<f16x4*>(xqh + off) = hv;
  *reinterpret_cast<f16x4*>(xql + off) = lv;
}

// ---------- K2: sim + top-k fused, per bj row-half block (XCD-paired) ----------
// Compute identical to r14 k_sim (2 blocks/CU, full rows per block).
// Epilogue (all data-parallel, short chains):
//  1) per-wave top-4 of its 64 cols: in-lane sort4 + 4-step 16-lane butterfly
//  2) 8KB LDS merge of 4 wave-quads -> thr per row (exact 4th largest)
//  3) ballot masks per 64-col block (bit layout == old k_topk m0..m3)
//  4) per-row deg/dis/nbr decode
// sim never touches HBM. All compared values identical to the old path.
__launch_bounds__(512, 4)
__global__ void k_sim(const _Float16* __restrict__ xqh, const _Float16* __restrict__ xql,
                      float* __restrict__ dis_o,
                      unsigned long long* __restrict__ mask_o,
                      unsigned char* __restrict__ nbr_o,
                      unsigned char* __restrict__ deg_o) {
  __shared__ __align__(16) char LB[65536];
  _Float16* Sh = (_Float16*)LB;                 // 32 KB
  _Float16* Sl = (_Float16*)(LB + 32768);       // 32 KB
  const int bid = blockIdx.x;
  const int g = bid >> 4, s_ = bid & 15;
  const int bj = g * 8 + (s_ & 7);              // 544 = 68*8 -> bijective
  const int rh = s_ >> 3;                       // row half 0/1
  const int tid = threadIdx.x, lane = tid & 63, wid = tid >> 6;
  const int wr = wid >> 2, wc = wid & 3;        // wave tile: 64 rows x 64 cols
  const int rowbase = rh * 128 + wr * 64;
  const int l15 = lane & 15, lg = lane >> 4;
  const size_t rb = (size_t)bj * 256;
  const size_t lsrc = (size_t)(lane >> 3) * 64 + (lane & 7) * 8;

  f32x4 acc[4][4];
  #pragma unroll
  for (int i = 0; i < 4; i++)
    #pragma unroll
    for (int j = 0; j < 4; j++) acc[i][j] = (f32x4){0.f, 0.f, 0.f, 0.f};

  for (int ks = 0; ks < 4; ++ks) {
    {
      const _Float16* ph = xqh + ((size_t)ks * FR + rb) * 64;
      const _Float16* pl = xql + ((size_t)ks * FR + rb) * 64;
      #pragma unroll
      for (int c = 0; c < 4; ++c) {
        const int row0 = (wid * 4 + c) * 8;
        gld16(ph + (size_t)row0 * 64 + lsrc, Sh + row0 * 64);
        gld16(pl + (size_t)row0 * 64 + lsrc, Sl + row0 * 64);
      }
    }
    __syncthreads();
    #pragma unroll
    for (int kh = 0; kh < 2; ++kh) {
      f16x8 bhv[4], blv[4];
      #pragma unroll
      for (int j = 0; j < 4; ++j) {
        int rc = wc * 64 + j * 16 + l15;
        int sl = ((kh * 4 + lg) ^ (rc & 7)) * 8;
        bhv[j] = *reinterpret_cast<const f16x8*>(&Sh[rc * 64 + sl]);
        blv[j] = *reinterpret_cast<const f16x8*>(&Sl[rc * 64 + sl]);
      }
      #pragma unroll
      for (int i = 0; i < 4; ++i) {
        int rl = rowbase + i * 16 + l15;
        int sl = ((kh * 4 + lg) ^ (rl & 7)) * 8;
        f16x8 ah = *reinterpret_cast<const f16x8*>(&Sh[rl * 64 + sl]);
        f16x8 al = *reinterpret_cast<const f16x8*>(&Sl[rl * 64 + sl]);
        #pragma unroll
        for (int j = 0; j < 4; ++j) {
          acc[i][j] = __builtin_amdgcn_mfma_f32_16x16x32_f16(ah, bhv[j], acc[i][j], 0, 0, 0);
          acc[i][j] = __builtin_amdgcn_mfma_f32_16x16x32_f16(ah, blv[j], acc[i][j], 0, 0, 0);
          acc[i][j] = __builtin_amdgcn_mfma_f32_16x16x32_f16(al, bhv[j], acc[i][j], 0, 0, 0);
        }
      }
    }
    __syncthreads();                            // also frees LB for the epilogue
  }

  // ---- fused top-k epilogue ----
  float* top4 = (float*)LB;                              // [128][4 wc][4]  8 KB
  unsigned long long* mlds = (unsigned long long*)(LB + 8192);  // [128][4]  4 KB
  float* thrl = (float*)(LB + 8192 + 4096);              // [128]           512 B

  // masked value accessor (cols >= 243 -> NEG_INF; only wc==3, j==3, l15>=3)
  auto mval = [&](int i, int j, int q) -> float {
    float x = acc[i][j][q];
    if (wc == 3 && j == 3 && l15 >= 3) x = NEG_INF;
    return x;
  };

  // (1) per-wave top-4 per row
  #pragma unroll
  for (int i = 0; i < 4; ++i) {
    #pragma unroll
    for (int q = 0; q < 4; ++q) {
      float v0 = mval(i, 0, q), v1 = mval(i, 1, q),
            v2 = mval(i, 2, q), v3 = mval(i, 3, q);
      { float mx, mn;
        mx=fmaxf(v0,v1); mn=fminf(v0,v1); v0=mx; v1=mn;
        mx=fmaxf(v2,v3); mn=fminf(v2,v3); v2=mx; v3=mn;
        mx=fmaxf(v0,v2); mn=fminf(v0,v2); v0=mx; v2=mn;
        mx=fmaxf(v1,v3); mn=fminf(v1,v3); v1=mx; v3=mn;
        mx=fmaxf(v1,v2); mn=fminf(v1,v2); v1=mx; v2=mn; }
      #pragma unroll
      for (int off = 1; off < 16; off <<= 1) {   // 16-lane butterfly (same lg group)
        float b0 = __shfl_xor(v0, off), b1 = __shfl_xor(v1, off),
              b2 = __shfl_xor(v2, off), b3 = __shfl_xor(v3, off);
        float t0 = fmaxf(v0, b3), t1 = fmaxf(v1, b2),
              t2 = fmaxf(v2, b1), t3 = fmaxf(v3, b0);
        float mx, mn;
        mx=fmaxf(t0,t2); mn=fminf(t0,t2); t0=mx; t2=mn;
        mx=fmaxf(t1,t3); mn=fminf(t1,t3); t1=mx; t3=mn;
        mx=fmaxf(t0,t1); mn=fminf(t0,t1); t0=mx; t1=mn;
        mx=fmaxf(t2,t3); mn=fminf(t2,t3); t2=mx; t3=mn;
        v0=t0; v1=t1; v2=t2; v3=t3;
      }
      if (l15 == 0) {
        int rloc = wr * 64 + i * 16 + lg * 4 + q;
        float* d = &top4[(rloc * 4 + wc) * 4];
        d[0] = v0; d[1] = v1; d[2] = v2; d[3] = v3;
      }
    }
  }
  __syncthreads();

  // (2) merge 4 wave-quads -> thr per row (one thread per row)
  if (tid < 128) {
    float t0 = NEG_INF, t1 = NEG_INF, t2 = NEG_INF, t3 = NEG_INF;
    #pragma unroll
    for (int w = 0; w < 4; ++w) {
      #pragma unroll
      for (int e = 0; e < 4; ++e) {
        float xv = top4[(tid * 4 + w) * 4 + e];
        if (xv > t3) {
          if (xv > t0)      { t3 = t2; t2 = t1; t1 = t0; t0 = xv; }
          else if (xv > t1) { t3 = t2; t2 = t1; t1 = xv; }
          else if (xv > t2) { t3 = t2; t2 = xv; }
          else              { t3 = xv; }
        }
      }
    }
    thrl[tid] = t3;
  }
  __syncthreads();

  // (3) ballot masks per 64-col block
  #pragma unroll
  for (int i = 0; i < 4; ++i) {
    #pragma unroll
    for (int q = 0; q < 4; ++q) {
      const int rloc = wr * 64 + i * 16 + lg * 4 + q;
      const float th = thrl[rloc];
      unsigned long long bal[4];
      #pragma unroll
      for (int j = 0; j < 4; ++j) bal[j] = __ballot(mval(i, j, q) >= th);
      if (l15 == 0) {
        unsigned long long m = 0;
        #pragma unroll
        for (int j = 0; j < 4; ++j)
          m |= ((bal[j] >> (lg * 16)) & 0xFFFFull) << (j * 16);
        mlds[rloc * 4 + wc] = m;
      }
    }
  }
  __syncthreads();

  // (4) per-row outputs
  if (tid < 128) {
    const int rn = rh * 128 + tid;
    if (rn < TT) {
      const size_t r = (size_t)bj * TT + rn;
      unsigned long long m0 = mlds[tid * 4 + 0], m1 = mlds[tid * 4 + 1],
                         m2 = mlds[tid * 4 + 2], m3 = mlds[tid * 4 + 3];
      int deg = __popcll(m0) + __popcll(m1) + __popcll(m2) + __popcll(m3);
      dis_o[r] = rsqrtf((float)deg);
      deg_o[r] = (unsigned char)((deg > 255) ? 255 : deg);
      mask_o[r * 4 + 0] = m0;
      mask_o[r * 4 + 1] = m1;
      mask_o[r * 4 + 2] = m2;
      mask_o[r * 4 + 3] = m3;
      unsigned long long nbv = 0;
      int cnt = 0;
      #pragma unroll
      for (int w4 = 0; w4 < 4; ++w4) {
        unsigned long long m = (w4 == 0) ? m0 : (w4 == 1) ? m1 : (w4 == 2) ? m2 : m3;
        while (m && cnt < 8) {
          int b = __ffsll(m) - 1;
          m &= m - 1;
          nbv |= ((unsigned long long)(w4 * 64 + b)) << (8 * cnt);
          ++cnt;
        }
      }
      *reinterpret_cast<unsigned long long*>(nbr_o + r * 8) = nbv;
    }
  }
}

// ---------- K1: u,v = x @ [Wu;Wv]^T + b  (f16 MFMA, staged, BK=64; r14 form) ----------
__launch_bounds__(256)
__global__ void k_uv(const _Float16* __restrict__ xqh, const _Float16* __restrict__ wcp,
                     const float* __restrict__ bu, const float* __restrict__ bv,
                     unsigned short* __restrict__ uo, unsigned short* __restrict__ vo) {
  __shared__ _Float16 S[2][128][64];             // A rows, B(weight) rows
  const int ct = blockIdx.x;                     // 0..3
  const int m0 = blockIdx.y * 128;               // padded flat row base
  const int tid = threadIdx.x, lane = tid & 63, wid = tid >> 6;
  const int rm = wid * 32;
  const int l15 = lane & 15, lg = lane >> 4;

  const float* bsrc = (ct < 2) ? bu : bv;
  unsigned short* osrc = (ct < 2) ? uo : vo;
  const int cb = (ct & 1) * 128;

  float bias[8];
  #pragma unroll
  for (int j = 0; j < 8; ++j) bias[j] = bsrc[cb + j * 16 + l15];

  f32x4 acc[2][8];
  #pragma unroll
  for (int i = 0; i < 2; i++)
    #pragma unroll
    for (int j = 0; j < 8; j++) acc[i][j] = (f32x4){0.f, 0.f, 0.f, 0.f};

  for (int ks = 0; ks < 4; ++ks) {
    #pragma unroll
    for (int c = 0; c < 8; ++c) {
      int ch = wid * 8 + c;
      int half = ch >> 4;
      int rows0 = (ch & 15) * 8;
      const _Float16* g = half
        ? wcp + ((size_t)ks * 512 + ct * 128 + rows0) * 64 + lane * 8
        : xqh + ((size_t)ks * FR  + m0       + rows0) * 64 + lane * 8;
      gld16(g, &S[half][rows0][0]);
    }
    __syncthreads();
    #pragma unroll
    for (int kh = 0; kh < 2; ++kh) {
      f16x8 af[2], bfv[8];
      #pragma unroll
      for (int i = 0; i < 2; ++i) {
        int rl = rm + i * 16 + l15;
        af[i] = *reinterpret_cast<const f16x8*>(&S[0][rl][((kh * 4 + lg) ^ (rl & 7)) * 8]);
      }
      #pragma unroll
      for (int j = 0; j < 8; ++j) {
        int rl = j * 16 + l15;
        bfv[j] = *reinterpret_cast<const f16x8*>(&S[1][rl][((kh * 4 + lg) ^ (rl & 7)) * 8]);
      }
      #pragma unroll
      for (int i = 0; i < 2; ++i)
        #pragma unroll
        for (int j = 0; j < 8; ++j)
          acc[i][j] = __builtin_amdgcn_mfma_f32_16x16x32_f16(af[i], bfv[j], acc[i][j], 0, 0, 0);
    }
    __syncthreads();
  }

  #pragma unroll
  for (int i = 0; i < 2; ++i) {
    #pragma unroll
    for (int q = 0; q < 4; ++q) {
      int gf = m0 + rm + i * 16 + lg * 4 + q;    // padded flat row
      int t = gf & 255, bj = gf >> 8;
      if (t < TT) {
        size_t gm = (size_t)bj * TT + t;         // compact row
        #pragma unroll
        for (int j = 0; j < 8; ++j)
          osrc[gm * CC + cb + j * 16 + l15] = f2bf(acc[i][j][q] + bias[j]);
      }
    }
  }
}

// ---------- K3b: h = norm_adj @ v + u  (list gather: independent loads) ----------
__launch_bounds__(512)
__global__ void k_agg(const unsigned char* __restrict__ nbr,
                      const unsigned char* __restrict__ degv,
                      const unsigned long long* __restrict__ mask,
                      const float* __restrict__ dis,
                      const unsigned short* __restrict__ u,
                      const unsigned short* __restrict__ v,
                      unsigned short* __restrict__ h,
                      float* __restrict__ p1, float* __restrict__ p2) {
  __shared__ float dis_l[256];
  const int bj = blockIdx.x;
  const int tid = threadIdx.x, lane = tid & 63, wid = tid >> 6;
  if (tid < TT) dis_l[tid] = dis[(size_t)bj * TT + tid];
  __syncthreads();
  const int start = blockIdx.y * 122;
  const int cnt = blockIdx.y ? (TT - 122) : 122;
  const size_t pbase = (size_t)bj * TT;
  const int co = lane * 4;
  for (int rl = wid; rl < cnt; rl += 8) {
    const int t = start + rl;
    const size_t r = pbase + t;
    const float dr = dis_l[t];
    const int dg = degv[r];
    const unsigned long long nb = *reinterpret_cast<const unsigned long long*>(nbr + r * 8);
    ushort4 uu = *reinterpret_cast<const ushort4*>(u + r * CC + co);
    float a0 = bf2f(uu.x), a1 = bf2f(uu.y), a2 = bf2f(uu.z), a3 = bf2f(uu.w);
    if (dg <= 8) {
      const int i0 = (int)(nb & 255), i1 = (int)((nb >> 8) & 255),
                i2 = (int)((nb >> 16) & 255), i3 = (int)((nb >> 24) & 255);
      ushort4 w0v = *reinterpret_cast<const ushort4*>(v + (pbase + i0) * CC + co);
      ushort4 w1v = *reinterpret_cast<const ushort4*>(v + (pbase + i1) * CC + co);
      ushort4 w2v = *reinterpret_cast<const ushort4*>(v + (pbase + i2) * CC + co);
      ushort4 w3v = *reinterpret_cast<const ushort4*>(v + (pbase + i3) * CC + co);
      const float w0 = dr * dis_l[i0], w1 = dr * dis_l[i1],
                  w2 = dr * dis_l[i2], w3 = dr * dis_l[i3];
      a0 = __builtin_fmaf(w0, bf2f(w0v.x), a0); a1 = __builtin_fmaf(w0, bf2f(w0v.y), a1);
      a2 = __builtin_fmaf(w0, bf2f(w0v.z), a2); a3 = __builtin_fmaf(w0, bf2f(w0v.w), a3);
      a0 = __builtin_fmaf(w1, bf2f(w1v.x), a0); a1 = __builtin_fmaf(w1, bf2f(w1v.y), a1);
      a2 = __builtin_fmaf(w1, bf2f(w1v.z), a2); a3 = __builtin_fmaf(w1, bf2f(w1v.w), a3);
      a0 = __builtin_fmaf(w2, bf2f(w2v.x), a0); a1 = __builtin_fmaf(w2, bf2f(w2v.y), a1);
      a2 = __builtin_fmaf(w2, bf2f(w2v.z), a2); a3 = __builtin_fmaf(w2, bf2f(w2v.w), a3);
      a0 = __builtin_fmaf(w3, bf2f(w3v.x), a0); a1 = __builtin_fmaf(w3, bf2f(w3v.y), a1);
      a2 = __builtin_fmaf(w3, bf2f(w3v.z), a2); a3 = __builtin_fmaf(w3, bf2f(w3v.w), a3);
      #pragma unroll
      for (int e = 4; e < 8; ++e) {
        if (e < dg) {
          const int ix = (int)((nb >> (8 * e)) & 255);
          const float we = dr * dis_l[ix];
          ushort4 vv = *reinterpret_cast<const ushort4*>(v + (pbase + ix) * CC + co);
          a0 = __builtin_fmaf(we, bf2f(vv.x), a0); a1 = __builtin_fmaf(we, bf2f(vv.y), a1);
          a2 = __builtin_fmaf(we, bf2f(vv.z), a2); a3 = __builtin_fmaf(we, bf2f(vv.w), a3);
        }
      }
    } else {                                     // rare tie overflow: mask decode
      #pragma unroll
      for (int w4 = 0; w4 < 4; ++w4) {
        unsigned long long m = mask[r * 4 + w4];
        while (m) {
          int i = __ffsll(m) - 1;
          m &= m - 1;
          int idx = w4 * 64 + i;
          float w = dr * dis_l[idx];
          ushort4 vv = *reinterpret_cast<const ushort4*>(v + (pbase + idx) * CC + co);
          a0 = __builtin_fmaf(w, bf2f(vv.x), a0);
          a1 = __builtin_fmaf(w, bf2f(vv.y), a1);
          a2 = __builtin_fmaf(w, bf2f(vv.z), a2);
          a3 = __builtin_fmaf(w, bf2f(vv.w), a3);
        }
      }
    }
    ushort4 hh;
    hh.x = f2bf(a0); hh.y = f2bf(a1); hh.z = f2bf(a2); hh.w = f2bf(a3);
    *reinterpret_cast<ushort4*>(h + r * CC + co) = hh;
    float s1 = a0 + a1 + a2 + a3;
    float s2 = a0*a0 + a1*a1 + a2*a2 + a3*a3;
    #pragma unroll
    for (int off = 1; off < 64; off <<= 1) { s1 += __shfl_xor(s1, off); s2 += __shfl_xor(s2, off); }
    if (lane == 0) { p1[r] = s1; p2[r] = s2; }
  }
}

// ---------- K4: BN stats per t -> scale/shift ----------
__global__ void k_bnstat(const float* __restrict__ p1, const float* __restrict__ p2,
                         const float* __restrict__ gamma, const float* __restrict__ beta,
                         float* __restrict__ scale, float* __restrict__ shift) {
  __shared__ float sA[256], sB[256];
  const int t = blockIdx.x;
  const int tid = threadIdx.x;
  float a = 0.f, b2 = 0.f;
  for (int bj = tid; bj < BJC; bj += 256) {
    a  += p1[bj * TT + t];
    b2 += p2[bj * TT + t];
  }
  sA[tid] = a; sB[tid] = b2;
  __syncthreads();
  for (int s = 128; s > 0; s >>= 1) {
    if (tid < s) { sA[tid] += sA[tid + s]; sB[tid] += sB[tid + s]; }
    __syncthreads();
  }
  if (tid == 0) {
    const float invN = 1.0f / (float)(BJC * CC);
    float mean = sA[0] * invN;
    float var  = sB[0] * invN - mean * mean;
    float sc   = rsqrtf(var + 1e-5f) * gamma[t];
    scale[t] = sc;
    shift[t] = beta[t] - mean * sc;
  }
}

// ---------- K5: out = relu(x + h*scale + shift), back to [B,T,J,C] ----------
__global__ void k_out(const float* __restrict__ x, const unsigned short* __restrict__ h,
                      const float* __restrict__ scale, const float* __restrict__ shift,
                      float* __restrict__ out) {
  int g = blockIdx.x * 256 + threadIdx.x;
  if (g >= MM * (CC/4)) return;
  int c4  = g & 63;
  int rowx = g >> 6;
  int b   = rowx / (TT*JJ);
  int rem = rowx - b*(TT*JJ);
  int t   = rem / JJ;
  int j   = rem - t*JJ;
  size_t hoff = ((size_t)(b*JJ + j) * TT + t) * CC + c4*4;
  float4 xv = *reinterpret_cast<const float4*>(x + (size_t)rowx*CC + c4*4);
  ushort4 hv = *reinterpret_cast<const ushort4*>(h + hoff);
  float sc = scale[t], sh = shift[t];
  float4 o;
  o.x = fmaxf(xv.x + bf2f(hv.x)*sc + sh, 0.f);
  o.y = fmaxf(xv.y + bf2f(hv.y)*sc + sh, 0.f);
  o.z = fmaxf(xv.z + bf2f(hv.z)*sc + sh, 0.f);
  o.w = fmaxf(xv.w + bf2f(hv.w)*sc + sh, 0.f);
  *reinterpret_cast<float4*>(out + (size_t)rowx*CC + c4*4) = o;
}

extern "C" void kernel_launch(void* const* d_in, const int* in_sizes, int n_in,
                              void* d_out, int out_size, void* d_ws, size_t ws_size,
                              hipStream_t stream) {
  const float* x     = (const float*)d_in[0];
  const float* Wu    = (const float*)d_in[1];
  const float* bu    = (const float*)d_in[2];
  const float* Wv    = (const float*)d_in[3];
  const float* bv    = (const float*)d_in[4];
  const float* gamma = (const float*)d_in[5];
  const float* beta  = (const float*)d_in[6];
  float* out = (float*)d_out;

  char* ws = (char*)d_ws;
  size_t off = 0;
  auto alloc = [&](size_t bytes) -> void* {
    void* p = ws + off;
    off = (off + bytes + 255) & ~(size_t)255;
    return p;
  };
  _Float16* xqh = (_Float16*)alloc((size_t)4 * FR * 64 * 2);      // 71.3MB
  _Float16* xql = (_Float16*)alloc((size_t)4 * FR * 64 * 2);      // 71.3MB
  _Float16* wcp = (_Float16*)alloc((size_t)4 * 512 * 64 * 2);
  float* dis = (float*)alloc((size_t)MM * 4);
  unsigned long long* msk = (unsigned long long*)alloc((size_t)MM * 4 * 8);
  unsigned char* nbr = (unsigned char*)alloc((size_t)MM * 8);
  unsigned char* deg = (unsigned char*)alloc((size_t)MM);
  float* p1    = (float*)alloc((size_t)MM * 4);
  float* p2    = (float*)alloc((size_t)MM * 4);
  float* scale = (float*)alloc(1024);
  float* shift = (float*)alloc(1024);
  unsigned short* u = (unsigned short*)alloc((size_t)MM * CC * 2); // 67.7MB
  unsigned short* v = (unsigned short*)alloc((size_t)MM * CC * 2); // 67.7MB
  // h aliases xql (dead after k_sim; k_agg runs later)
  unsigned short* h = (unsigned short*)xql;

  if (ws_size < off) {
    hipMemsetAsync(d_out, 0, (size_t)out_size * 4, stream);
    return;
  }

  k_prep_w<<<dim3(512/4), dim3(256), 0, stream>>>(Wu, Wv, wcp);
  k_prep_x<<<dim3(MM/4), dim3(256), 0, stream>>>(x, xqh, xql);
  k_sim  <<<dim3(BJC*2), dim3(512), 0, stream>>>(xqh, xql, dis, msk, nbr, deg);
  k_uv   <<<dim3(4, FR/128), dim3(256), 0, stream>>>(xqh, wcp, bu, bv, u, v);
  k_agg  <<<dim3(BJC, 2), dim3(512), 0, stream>>>(nbr, deg, msk, dis, u, v, h, p1, p2);
  k_bnstat<<<dim3(TT), dim3(256), 0, stream>>>(p1, p2, gamma, beta, scale, shift);
  k_out  <<<dim3((MM*(CC/4) + 255)/256), dim3(256), 0, stream>>>(x, h, scale, shift, out);
}

// Round 18
// 331.273 us; speedup vs baseline: 1.2201x; 1.0209x over previous
//
#include <hip/hip_runtime.h>

#define BB 32
#define TT 243
#define JJ 17
#define CC 256
#define BJC (BB*JJ)          // 544
#define MM (BJC*TT)          // 132192 rows (compact: r = bj*TT + t)
#define FR (BJC*256)         // 139264 padded flat rows: flat = bj*256 + t
#define NEG_INF (-3.0e38f)

typedef __attribute__((ext_vector_type(8))) short bf16x8;
typedef __attribute__((ext_vector_type(4))) float f32x4;
typedef __attribute__((ext_vector_type(8))) _Float16 f16x8;
typedef __attribute__((ext_vector_type(4))) _Float16 f16x4;

__device__ __forceinline__ unsigned short f2bf(float f) {
  unsigned int u = __float_as_uint(f);
  u = (u + 0x7fffu + ((u >> 16) & 1u)) >> 16;   // RNE
  return (unsigned short)u;
}
__device__ __forceinline__ float bf2f(unsigned short s) {
  return __uint_as_float(((unsigned int)s) << 16);
}

// async global->LDS, 16B per lane: lds dest = uniform base + lane*16
__device__ __forceinline__ void gld16(const void* g, void* l) {
  __builtin_amdgcn_global_load_lds(
      (__attribute__((address_space(1))) void*)(g),
      (__attribute__((address_space(3))) void*)(l), 16, 0, 0);
}

// ---------- K0a: W_u,W_v f32 [C,C] -> wcp f16 [4 ksteps][512][64] (swizzled) ----------
__launch_bounds__(256)
__global__ void k_prep_w(const float* __restrict__ Wu, const float* __restrict__ Wv,
                         _Float16* __restrict__ wcp) {
  const int r = blockIdx.x * 4 + (threadIdx.x >> 6);   // 0..511
  const int l = threadIdx.x & 63;
  const float* src = ((r < CC) ? (Wu + (size_t)r * CC) : (Wv + (size_t)(r - CC) * CC)) + l * 4;
  float4 v = *reinterpret_cast<const float4*>(src);
  f16x4 hv = (f16x4){(_Float16)v.x, (_Float16)v.y, (_Float16)v.z, (_Float16)v.w};
  const int ks = l >> 4;                 // k-plane 0..3 (64 f16 each)
  const int u  = (l & 15) >> 1;          // 16B unit 0..7
  const int s  = u ^ (r & 7);            // bank swizzle slot
  *reinterpret_cast<f16x4*>(wcp + ((size_t)ks * 512 + r) * 64 + s * 8 + (l & 1) * 4) = hv;
}

// ---------- K0b: x -> xqh/xql (f16 hi + residual lo), panel-padded flat layout ----------
__launch_bounds__(256)
__global__ void k_prep_x(const float* __restrict__ x,
                         _Float16* __restrict__ xqh, _Float16* __restrict__ xql) {
  const int r = blockIdx.x * 4 + (threadIdx.x >> 6);   // compact row 0..MM-1
  const int l = threadIdx.x & 63;
  const int bj = r / TT, t = r - bj * TT;
  const int b = bj / JJ, j = bj - b * JJ;
  float4 v = *reinterpret_cast<const float4*>(
      x + ((size_t)(b * TT + t) * JJ + j) * CC + l * 4);
  _Float16 h0 = (_Float16)v.x, h1 = (_Float16)v.y, h2 = (_Float16)v.z, h3 = (_Float16)v.w;
  f16x4 hv = (f16x4){h0, h1, h2, h3};
  f16x4 lv = (f16x4){(_Float16)(v.x - (float)h0), (_Float16)(v.y - (float)h1),
                     (_Float16)(v.z - (float)h2), (_Float16)(v.w - (float)h3)};
  const int fr = bj * 256 + t;            // padded flat row
  const int ks = l >> 4;
  const int u  = (l & 15) >> 1;
  const int s  = u ^ (t & 7);             // == fr&7 since bj*256 % 8 == 0
  const size_t off = ((size_t)ks * FR + fr) * 64 + s * 8 + (l & 1) * 4;
  *reinterpret_cast<f16x4*>(xqh + off) = hv;
  *reinterpret_cast<f16x4*>(xql + off) = lv;
}

// ---------- K2: sim + top-k fused, per bj row-half block (XCD-paired) ----------
__launch_bounds__(512, 4)
__global__ void k_sim(const _Float16* __restrict__ xqh, const _Float16* __restrict__ xql,
                      float* __restrict__ dis_o,
                      unsigned long long* __restrict__ mask_o,
                      unsigned char* __restrict__ nbr_o,
                      unsigned char* __restrict__ deg_o) {
  __shared__ __align__(16) char LB[65536];
  _Float16* Sh = (_Float16*)LB;                 // 32 KB
  _Float16* Sl = (_Float16*)(LB + 32768);       // 32 KB
  const int bid = blockIdx.x;
  const int g = bid >> 4, s_ = bid & 15;
  const int bj = g * 8 + (s_ & 7);              // 544 = 68*8 -> bijective
  const int rh = s_ >> 3;                       // row half 0/1
  const int tid = threadIdx.x, lane = tid & 63, wid = tid >> 6;
  const int wr = wid >> 2, wc = wid & 3;        // wave tile: 64 rows x 64 cols
  const int rowbase = rh * 128 + wr * 64;
  const int l15 = lane & 15, lg = lane >> 4;
  const size_t rb = (size_t)bj * 256;
  const size_t lsrc = (size_t)(lane >> 3) * 64 + (lane & 7) * 8;

  f32x4 acc[4][4];
  #pragma unroll
  for (int i = 0; i < 4; i++)
    #pragma unroll
    for (int j = 0; j < 4; j++) acc[i][j] = (f32x4){0.f, 0.f, 0.f, 0.f};

  for (int ks = 0; ks < 4; ++ks) {
    {
      const _Float16* ph = xqh + ((size_t)ks * FR + rb) * 64;
      const _Float16* pl = xql + ((size_t)ks * FR + rb) * 64;
      #pragma unroll
      for (int c = 0; c < 4; ++c) {
        const int row0 = (wid * 4 + c) * 8;
        gld16(ph + (size_t)row0 * 64 + lsrc, Sh + row0 * 64);
        gld16(pl + (size_t)row0 * 64 + lsrc, Sl + row0 * 64);
      }
    }
    __syncthreads();
    #pragma unroll
    for (int kh = 0; kh < 2; ++kh) {
      f16x8 bhv[4], blv[4];
      #pragma unroll
      for (int j = 0; j < 4; ++j) {
        int rc = wc * 64 + j * 16 + l15;
        int sl = ((kh * 4 + lg) ^ (rc & 7)) * 8;
        bhv[j] = *reinterpret_cast<const f16x8*>(&Sh[rc * 64 + sl]);
        blv[j] = *reinterpret_cast<const f16x8*>(&Sl[rc * 64 + sl]);
      }
      #pragma unroll
      for (int i = 0; i < 4; ++i) {
        int rl = rowbase + i * 16 + l15;
        int sl = ((kh * 4 + lg) ^ (rl & 7)) * 8;
        f16x8 ah = *reinterpret_cast<const f16x8*>(&Sh[rl * 64 + sl]);
        f16x8 al = *reinterpret_cast<const f16x8*>(&Sl[rl * 64 + sl]);
        #pragma unroll
        for (int j = 0; j < 4; ++j) {
          acc[i][j] = __builtin_amdgcn_mfma_f32_16x16x32_f16(ah, bhv[j], acc[i][j], 0, 0, 0);
          acc[i][j] = __builtin_amdgcn_mfma_f32_16x16x32_f16(ah, blv[j], acc[i][j], 0, 0, 0);
          acc[i][j] = __builtin_amdgcn_mfma_f32_16x16x32_f16(al, bhv[j], acc[i][j], 0, 0, 0);
        }
      }
    }
    __syncthreads();                            // also frees LB for the epilogue
  }

  // ---- fused top-k epilogue ----
  float* top4 = (float*)LB;                              // [128][4 wc][4]  8 KB
  unsigned long long* mlds = (unsigned long long*)(LB + 8192);  // [128][4]  4 KB
  float* thrl = (float*)(LB + 8192 + 4096);              // [128]           512 B

  auto mval = [&](int i, int j, int q) -> float {
    float x = acc[i][j][q];
    if (wc == 3 && j == 3 && l15 >= 3) x = NEG_INF;
    return x;
  };

  // (1) per-wave top-4 per row
  #pragma unroll
  for (int i = 0; i < 4; ++i) {
    #pragma unroll
    for (int q = 0; q < 4; ++q) {
      float v0 = mval(i, 0, q), v1 = mval(i, 1, q),
            v2 = mval(i, 2, q), v3 = mval(i, 3, q);
      { float mx, mn;
        mx=fmaxf(v0,v1); mn=fminf(v0,v1); v0=mx; v1=mn;
        mx=fmaxf(v2,v3); mn=fminf(v2,v3); v2=mx; v3=mn;
        mx=fmaxf(v0,v2); mn=fminf(v0,v2); v0=mx; v2=mn;
        mx=fmaxf(v1,v3); mn=fminf(v1,v3); v1=mx; v3=mn;
        mx=fmaxf(v1,v2); mn=fminf(v1,v2); v1=mx; v2=mn; }
      #pragma unroll
      for (int off = 1; off < 16; off <<= 1) {   // 16-lane butterfly
        float b0 = __shfl_xor(v0, off), b1 = __shfl_xor(v1, off),
              b2 = __shfl_xor(v2, off), b3 = __shfl_xor(v3, off);
        float t0 = fmaxf(v0, b3), t1 = fmaxf(v1, b2),
              t2 = fmaxf(v2, b1), t3 = fmaxf(v3, b0);
        float mx, mn;
        mx=fmaxf(t0,t2); mn=fminf(t0,t2); t0=mx; t2=mn;
        mx=fmaxf(t1,t3); mn=fminf(t1,t3); t1=mx; t3=mn;
        mx=fmaxf(t0,t1); mn=fminf(t0,t1); t0=mx; t1=mn;
        mx=fmaxf(t2,t3); mn=fminf(t2,t3); t2=mx; t3=mn;
        v0=t0; v1=t1; v2=t2; v3=t3;
      }
      if (l15 == 0) {
        int rloc = wr * 64 + i * 16 + lg * 4 + q;
        float* d = &top4[(rloc * 4 + wc) * 4];
        d[0] = v0; d[1] = v1; d[2] = v2; d[3] = v3;
      }
    }
  }
  __syncthreads();

  // (2) merge 4 wave-quads -> thr per row
  if (tid < 128) {
    float t0 = NEG_INF, t1 = NEG_INF, t2 = NEG_INF, t3 = NEG_INF;
    #pragma unroll
    for (int w = 0; w < 4; ++w) {
      #pragma unroll
      for (int e = 0; e < 4; ++e) {
        float xv = top4[(tid * 4 + w) * 4 + e];
        if (xv > t3) {
          if (xv > t0)      { t3 = t2; t2 = t1; t1 = t0; t0 = xv; }
          else if (xv > t1) { t3 = t2; t2 = t1; t1 = xv; }
          else if (xv > t2) { t3 = t2; t2 = xv; }
          else              { t3 = xv; }
        }
      }
    }
    thrl[tid] = t3;
  }
  __syncthreads();

  // (3) ballot masks per 64-col block
  #pragma unroll
  for (int i = 0; i < 4; ++i) {
    #pragma unroll
    for (int q = 0; q < 4; ++q) {
      const int rloc = wr * 64 + i * 16 + lg * 4 + q;
      const float th = thrl[rloc];
      unsigned long long bal[4];
      #pragma unroll
      for (int j = 0; j < 4; ++j) bal[j] = __ballot(mval(i, j, q) >= th);
      if (l15 == 0) {
        unsigned long long m = 0;
        #pragma unroll
        for (int j = 0; j < 4; ++j)
          m |= ((bal[j] >> (lg * 16)) & 0xFFFFull) << (j * 16);
        mlds[rloc * 4 + wc] = m;
      }
    }
  }
  __syncthreads();

  // (4) per-row outputs
  if (tid < 128) {
    const int rn = rh * 128 + tid;
    if (rn < TT) {
      const size_t r = (size_t)bj * TT + rn;
      unsigned long long m0 = mlds[tid * 4 + 0], m1 = mlds[tid * 4 + 1],
                         m2 = mlds[tid * 4 + 2], m3 = mlds[tid * 4 + 3];
      int deg = __popcll(m0) + __popcll(m1) + __popcll(m2) + __popcll(m3);
      dis_o[r] = rsqrtf((float)deg);
      deg_o[r] = (unsigned char)((deg > 255) ? 255 : deg);
      mask_o[r * 4 + 0] = m0;
      mask_o[r * 4 + 1] = m1;
      mask_o[r * 4 + 2] = m2;
      mask_o[r * 4 + 3] = m3;
      unsigned long long nbv = 0;
      int cnt = 0;
      #pragma unroll
      for (int w4 = 0; w4 < 4; ++w4) {
        unsigned long long m = (w4 == 0) ? m0 : (w4 == 1) ? m1 : (w4 == 2) ? m2 : m3;
        while (m && cnt < 8) {
          int b = __ffsll(m) - 1;
          m &= m - 1;
          nbv |= ((unsigned long long)(w4 * 64 + b)) << (8 * cnt);
          ++cnt;
        }
      }
      *reinterpret_cast<unsigned long long*>(nbr_o + r * 8) = nbv;
    }
  }
}

// ---------- K1: u,v = x @ [Wu;Wv]^T + b  (jh-split for 4 waves/SIMD) ----------
__launch_bounds__(256, 4)
__global__ void k_uv(const _Float16* __restrict__ xqh, const _Float16* __restrict__ wcp,
                     const float* __restrict__ bu, const float* __restrict__ bv,
                     unsigned short* __restrict__ uo, unsigned short* __restrict__ vo) {
  __shared__ _Float16 S[2][128][64];             // A rows, B(weight) rows
  const int ct = blockIdx.x;                     // 0..3
  const int m0 = blockIdx.y * 128;               // padded flat row base
  const int tid = threadIdx.x, lane = tid & 63, wid = tid >> 6;
  const int rm = wid * 32;
  const int l15 = lane & 15, lg = lane >> 4;

  const float* bsrc = (ct < 2) ? bu : bv;
  unsigned short* osrc = (ct < 2) ? uo : vo;
  const int cb = (ct & 1) * 128;

  f32x4 acc[2][8];
  #pragma unroll
  for (int i = 0; i < 2; i++)
    #pragma unroll
    for (int j = 0; j < 8; j++) acc[i][j] = (f32x4){0.f, 0.f, 0.f, 0.f};

  for (int ks = 0; ks < 4; ++ks) {
    #pragma unroll
    for (int c = 0; c < 8; ++c) {
      int ch = wid * 8 + c;
      int half = ch >> 4;
      int rows0 = (ch & 15) * 8;
      const _Float16* g = half
        ? wcp + ((size_t)ks * 512 + ct * 128 + rows0) * 64 + lane * 8
        : xqh + ((size_t)ks * FR  + m0       + rows0) * 64 + lane * 8;
      gld16(g, &S[half][rows0][0]);
    }
    __syncthreads();
    #pragma unroll
    for (int kh = 0; kh < 2; ++kh) {
      f16x8 af[2];
      #pragma unroll
      for (int i = 0; i < 2; ++i) {
        int rl = rm + i * 16 + l15;
        af[i] = *reinterpret_cast<const f16x8*>(&S[0][rl][((kh * 4 + lg) ^ (rl & 7)) * 8]);
      }
      #pragma unroll
      for (int jh = 0; jh < 2; ++jh) {           // split: only 4 bfv live
        f16x8 bfv[4];
        #pragma unroll
        for (int j = 0; j < 4; ++j) {
          int rl = (jh * 4 + j) * 16 + l15;
          bfv[j] = *reinterpret_cast<const f16x8*>(&S[1][rl][((kh * 4 + lg) ^ (rl & 7)) * 8]);
        }
        #pragma unroll
        for (int i = 0; i < 2; ++i)
          #pragma unroll
          for (int j = 0; j < 4; ++j)
            acc[i][jh * 4 + j] =
              __builtin_amdgcn_mfma_f32_16x16x32_f16(af[i], bfv[j], acc[i][jh * 4 + j], 0, 0, 0);
      }
    }
    __syncthreads();
  }

  float bias[8];
  #pragma unroll
  for (int j = 0; j < 8; ++j) bias[j] = bsrc[cb + j * 16 + l15];

  #pragma unroll
  for (int i = 0; i < 2; ++i) {
    #pragma unroll
    for (int q = 0; q < 4; ++q) {
      int gf = m0 + rm + i * 16 + lg * 4 + q;    // padded flat row
      int t = gf & 255, bj = gf >> 8;
      if (t < TT) {
        size_t gm = (size_t)bj * TT + t;         // compact row
        #pragma unroll
        for (int j = 0; j < 8; ++j)
          osrc[gm * CC + cb + j * 16 + l15] = f2bf(acc[i][j][q] + bias[j]);
      }
    }
  }
}

// ---------- K3b: h = norm_adj @ v + u  (list gather: independent loads) ----------
__launch_bounds__(512)
__global__ void k_agg(const unsigned char* __restrict__ nbr,
                      const unsigned char* __restrict__ degv,
                      const unsigned long long* __restrict__ mask,
                      const float* __restrict__ dis,
                      const unsigned short* __restrict__ u,
                      const unsigned short* __restrict__ v,
                      unsigned short* __restrict__ h,
                      float* __restrict__ p1, float* __restrict__ p2) {
  __shared__ float dis_l[256];
  const int bj = blockIdx.x;
  const int tid = threadIdx.x, lane = tid & 63, wid = tid >> 6;
  if (tid < TT) dis_l[tid] = dis[(size_t)bj * TT + tid];
  __syncthreads();
  const int start = blockIdx.y * 122;
  const int cnt = blockIdx.y ? (TT - 122) : 122;
  const size_t pbase = (size_t)bj * TT;
  const int co = lane * 4;
  for (int rl = wid; rl < cnt; rl += 8) {
    const int t = start + rl;
    const size_t r = pbase + t;
    const float dr = dis_l[t];
    const int dg = degv[r];
    const unsigned long long nb = *reinterpret_cast<const unsigned long long*>(nbr + r * 8);
    ushort4 uu = *reinterpret_cast<const ushort4*>(u + r * CC + co);
    float a0 = bf2f(uu.x), a1 = bf2f(uu.y), a2 = bf2f(uu.z), a3 = bf2f(uu.w);
    if (dg <= 8) {
      const int i0 = (int)(nb & 255), i1 = (int)((nb >> 8) & 255),
                i2 = (int)((nb >> 16) & 255), i3 = (int)((nb >> 24) & 255);
      ushort4 w0v = *reinterpret_cast<const ushort4*>(v + (pbase + i0) * CC + co);
      ushort4 w1v = *reinterpret_cast<const ushort4*>(v + (pbase + i1) * CC + co);
      ushort4 w2v = *reinterpret_cast<const ushort4*>(v + (pbase + i2) * CC + co);
      ushort4 w3v = *reinterpret_cast<const ushort4*>(v + (pbase + i3) * CC + co);
      const float w0 = dr * dis_l[i0], w1 = dr * dis_l[i1],
                  w2 = dr * dis_l[i2], w3 = dr * dis_l[i3];
      a0 = __builtin_fmaf(w0, bf2f(w0v.x), a0); a1 = __builtin_fmaf(w0, bf2f(w0v.y), a1);
      a2 = __builtin_fmaf(w0, bf2f(w0v.z), a2); a3 = __builtin_fmaf(w0, bf2f(w0v.w), a3);
      a0 = __builtin_fmaf(w1, bf2f(w1v.x), a0); a1 = __builtin_fmaf(w1, bf2f(w1v.y), a1);
      a2 = __builtin_fmaf(w1, bf2f(w1v.z), a2); a3 = __builtin_fmaf(w1, bf2f(w1v.w), a3);
      a0 = __builtin_fmaf(w2, bf2f(w2v.x), a0); a1 = __builtin_fmaf(w2, bf2f(w2v.y), a1);
      a2 = __builtin_fmaf(w2, bf2f(w2v.z), a2); a3 = __builtin_fmaf(w2, bf2f(w2v.w), a3);
      a0 = __builtin_fmaf(w3, bf2f(w3v.x), a0); a1 = __builtin_fmaf(w3, bf2f(w3v.y), a1);
      a2 = __builtin_fmaf(w3, bf2f(w3v.z), a2); a3 = __builtin_fmaf(w3, bf2f(w3v.w), a3);
      #pragma unroll
      for (int e = 4; e < 8; ++e) {
        if (e < dg) {
          const int ix = (int)((nb >> (8 * e)) & 255);
          const float we = dr * dis_l[ix];
          ushort4 vv = *reinterpret_cast<const ushort4*>(v + (pbase + ix) * CC + co);
          a0 = __builtin_fmaf(we, bf2f(vv.x), a0); a1 = __builtin_fmaf(we, bf2f(vv.y), a1);
          a2 = __builtin_fmaf(we, bf2f(vv.z), a2); a3 = __builtin_fmaf(we, bf2f(vv.w), a3);
        }
      }
    } else {                                     // rare tie overflow: mask decode
      #pragma unroll
      for (int w4 = 0; w4 < 4; ++w4) {
        unsigned long long m = mask[r * 4 + w4];
        while (m) {
          int i = __ffsll(m) - 1;
          m &= m - 1;
          int idx = w4 * 64 + i;
          float w = dr * dis_l[idx];
          ushort4 vv = *reinterpret_cast<const ushort4*>(v + (pbase + idx) * CC + co);
          a0 = __builtin_fmaf(w, bf2f(vv.x), a0);
          a1 = __builtin_fmaf(w, bf2f(vv.y), a1);
          a2 = __builtin_fmaf(w, bf2f(vv.z), a2);
          a3 = __builtin_fmaf(w, bf2f(vv.w), a3);
        }
      }
    }
    ushort4 hh;
    hh.x = f2bf(a0); hh.y = f2bf(a1); hh.z = f2bf(a2); hh.w = f2bf(a3);
    *reinterpret_cast<ushort4*>(h + r * CC + co) = hh;
    float s1 = a0 + a1 + a2 + a3;
    float s2 = a0*a0 + a1*a1 + a2*a2 + a3*a3;
    #pragma unroll
    for (int off = 1; off < 64; off <<= 1) { s1 += __shfl_xor(s1, off); s2 += __shfl_xor(s2, off); }
    if (lane == 0) { p1[r] = s1; p2[r] = s2; }
  }
}

// ---------- K4: BN stats per t -> scale/shift ----------
__global__ void k_bnstat(const float* __restrict__ p1, const float* __restrict__ p2,
                         const float* __restrict__ gamma, const float* __restrict__ beta,
                         float* __restrict__ scale, float* __restrict__ shift) {
  __shared__ float sA[256], sB[256];
  const int t = blockIdx.x;
  const int tid = threadIdx.x;
  float a = 0.f, b2 = 0.f;
  for (int bj = tid; bj < BJC; bj += 256) {
    a  += p1[bj * TT + t];
    b2 += p2[bj * TT + t];
  }
  sA[tid] = a; sB[tid] = b2;
  __syncthreads();
  for (int s = 128; s > 0; s >>= 1) {
    if (tid < s) { sA[tid] += sA[tid + s]; sB[tid] += sB[tid + s]; }
    __syncthreads();
  }
  if (tid == 0) {
    const float invN = 1.0f / (float)(BJC * CC);
    float mean = sA[0] * invN;
    float var  = sB[0] * invN - mean * mean;
    float sc   = rsqrtf(var + 1e-5f) * gamma[t];
    scale[t] = sc;
    shift[t] = beta[t] - mean * sc;
  }
}

// ---------- K5: out = relu(xqh + h*scale + shift), 8 channels/thread ----------
// Residual uses the f16 hi-plane (err <= 2^-11|x| ~ 5e-4, negligible vs bf16 noise).
__launch_bounds__(256)
__global__ void k_out(const _Float16* __restrict__ xqh, const unsigned short* __restrict__ h,
                      const float* __restrict__ scale, const float* __restrict__ shift,
                      float* __restrict__ out) {
  int gth = blockIdx.x * 256 + threadIdx.x;      // one 8-channel unit per thread
  if (gth >= MM * 32) return;
  int c8   = gth & 31;
  int rowx = gth >> 5;                           // (b*TT + t)*JJ + j
  int b   = rowx / (TT*JJ);
  int rem = rowx - b*(TT*JJ);
  int t   = rem / JJ;
  int j   = rem - t*JJ;
  int bj  = b * JJ + j;
  const int ks = c8 >> 3, un = c8 & 7, sl = un ^ (t & 7);
  f16x8 xv = *reinterpret_cast<const f16x8*>(
      xqh + ((size_t)ks * FR + (size_t)bj * 256 + t) * 64 + sl * 8);
  const unsigned short* hp = h + ((size_t)bj * TT + t) * CC + c8 * 8;
  ushort4 h0 = *reinterpret_cast<const ushort4*>(hp);
  ushort4 h1 = *reinterpret_cast<const ushort4*>(hp + 4);
  float sc = scale[t], sh = shift[t];
  float4 o0, o1;
  o0.x = fmaxf((float)xv[0] + bf2f(h0.x) * sc + sh, 0.f);
  o0.y = fmaxf((float)xv[1] + bf2f(h0.y) * sc + sh, 0.f);
  o0.z = fmaxf((float)xv[2] + bf2f(h0.z) * sc + sh, 0.f);
  o0.w = fmaxf((float)xv[3] + bf2f(h0.w) * sc + sh, 0.f);
  o1.x = fmaxf((float)xv[4] + bf2f(h1.x) * sc + sh, 0.f);
  o1.y = fmaxf((float)xv[5] + bf2f(h1.y) * sc + sh, 0.f);
  o1.z = fmaxf((float)xv[6] + bf2f(h1.z) * sc + sh, 0.f);
  o1.w = fmaxf((float)xv[7] + bf2f(h1.w) * sc + sh, 0.f);
  float* op = out + (size_t)rowx * CC + c8 * 8;
  *reinterpret_cast<float4*>(op)     = o0;
  *reinterpret_cast<float4*>(op + 4) = o1;
}

extern "C" void kernel_launch(void* const* d_in, const int* in_sizes, int n_in,
                              void* d_out, int out_size, void* d_ws, size_t ws_size,
                              hipStream_t stream) {
  const float* x     = (const float*)d_in[0];
  const float* Wu    = (const float*)d_in[1];
  const float* bu    = (const float*)d_in[2];
  const float* Wv    = (const float*)d_in[3];
  const float* bv    = (const float*)d_in[4];
  const float* gamma = (const float*)d_in[5];
  const float* beta  = (const float*)d_in[6];
  float* out = (float*)d_out;

  char* ws = (char*)d_ws;
  size_t off = 0;
  auto alloc = [&](size_t bytes) -> void* {
    void* p = ws + off;
    off = (off + bytes + 255) & ~(size_t)255;
    return p;
  };
  _Float16* xqh = (_Float16*)alloc((size_t)4 * FR * 64 * 2);      // 71.3MB
  _Float16* xql = (_Float16*)alloc((size_t)4 * FR * 64 * 2);      // 71.3MB
  _Float16* wcp = (_Float16*)alloc((size_t)4 * 512 * 64 * 2);
  float* dis = (float*)alloc((size_t)MM * 4);
  unsigned long long* msk = (unsigned long long*)alloc((size_t)MM * 4 * 8);
  unsigned char* nbr = (unsigned char*)alloc((size_t)MM * 8);
  unsigned char* deg = (unsigned char*)alloc((size_t)MM);
  float* p1    = (float*)alloc((size_t)MM * 4);
  float* p2    = (float*)alloc((size_t)MM * 4);
  float* scale = (float*)alloc(1024);
  float* shift = (float*)alloc(1024);
  unsigned short* u = (unsigned short*)alloc((size_t)MM * CC * 2); // 67.7MB
  unsigned short* v = (unsigned short*)alloc((size_t)MM * CC * 2); // 67.7MB
  // h aliases xql (dead after k_sim; k_agg runs later)
  unsigned short* h = (unsigned short*)xql;

  if (ws_size < off) {
    hipMemsetAsync(d_out, 0, (size_t)out_size * 4, stream);
    return;
  }

  k_prep_w<<<dim3(512/4), dim3(256), 0, stream>>>(Wu, Wv, wcp);
  k_prep_x<<<dim3(MM/4), dim3(256), 0, stream>>>(x, xqh, xql);
  k_sim  <<<dim3(BJC*2), dim3(512), 0, stream>>>(xqh, xql, dis, msk, nbr, deg);
  k_uv   <<<dim3(4, FR/128), dim3(256), 0, stream>>>(xqh, wcp, bu, bv, u, v);
  k_agg  <<<dim3(BJC, 2), dim3(512), 0, stream>>>(nbr, deg, msk, dis, u, v, h, p1, p2);
  k_bnstat<<<dim3(TT), dim3(256), 0, stream>>>(p1, p2, gamma, beta, scale, shift);
  k_out  <<<dim3((MM*32 + 255)/256), dim3(256), 0, stream>>>(xqh, h, scale, shift, out);
}